// Round 6
// baseline (196.454 us; speedup 1.0000x reference)
//
#include <hip/hip_runtime.h>
#include <hip/hip_bf16.h>

// B=8, S=2048, E=1024, H=64. fp32 in/out, bf16 MFMA compute.
// conv_w: W->bf16. qkv_mfma: m32 x n192 x k1024 GEMM; x staged via
// double-buffered LDS (1 barrier/chunk), W frags direct from global
// (L1-resident 24KB/chunk working set); 512 thr, grid 512 -> 4 waves/SIMD.
// attn_mfma: transposed-S flash attention (q in lanes, k in regs, fixed-max
// softmax, register PV via 16x16x16), 8 waves/block + explicit K prefetch.

#define BB 8
#define SS 2048
#define EE 1024
#define HH 64
#define MM (BB * SS)

typedef __bf16 bf16;
typedef __attribute__((ext_vector_type(8))) __bf16 bf16x8;
typedef __attribute__((ext_vector_type(4))) __bf16 bf16x4;
typedef __attribute__((ext_vector_type(4))) float f32x4;
typedef __attribute__((ext_vector_type(4))) short short4v;

// ---------------------------------------------------------------------------
// [Wq;Wk;Wv] (192x1024 fp32) -> Wb (bf16). 96 blocks.
// ---------------------------------------------------------------------------
__global__ __launch_bounds__(256) void conv_w(const float* __restrict__ Wq,
                                              const float* __restrict__ Wk,
                                              const float* __restrict__ Wv,
                                              bf16* __restrict__ Wb) {
    int i = (blockIdx.x * 256 + threadIdx.x) * 8;
    const float* src;
    int j;
    if (i < 65536)        { src = Wq; j = i; }
    else if (i < 131072)  { src = Wk; j = i - 65536; }
    else                  { src = Wv; j = i - 131072; }
    f32x4 a = *(const f32x4*)(src + j);
    f32x4 b = *(const f32x4*)(src + j + 4);
    bf16x8 o = {(bf16)a.x, (bf16)a.y, (bf16)a.z, (bf16)a.w,
                (bf16)b.x, (bf16)b.y, (bf16)b.z, (bf16)b.w};
    *(bf16x8*)(Wb + i) = o;
}

// ---------------------------------------------------------------------------
// QKV GEMM. Block = 512 thr (8 waves), m-tile 32. Wave w: m-subtile (w&1),
// n-group (w>>1) (3 n-tiles of the 12: 0..3 Q, 4..7 K, 8..11 V).
// x: fp32 global -> reg (prefetched) -> bf16 LDS, double-buffered, one
// barrier per BK=64 chunk. W frags: direct global bf16x8 loads (24 KB/chunk
// working set, L1-resident, shared across waves). Grid 512 -> 2 blocks/CU,
// 16 waves/CU = 4 waves/SIMD.
// ---------------------------------------------------------------------------
__global__ __launch_bounds__(512) void qkv_mfma(
    const float* __restrict__ x, const bf16* __restrict__ Wb,
    const float* __restrict__ bq, const float* __restrict__ bk,
    const float* __restrict__ bv,
    bf16* __restrict__ Q, bf16* __restrict__ K, bf16* __restrict__ Vt) {
    __shared__ __align__(16) bf16 Abuf[2][32][72];  // 9.2 KB

    const int tid  = threadIdx.x;
    const int wave = tid >> 6;
    const int lane = tid & 63;
    const int col  = lane & 15;
    const int quad = lane >> 4;
    const int m0   = blockIdx.x * 32;
    const int msub = wave & 1;
    const int grp  = wave >> 1;

    const int arow = tid >> 4;          // 0..31
    const int akq  = (tid & 15) * 4;    // 0..60

    f32x4 acc[3];
#pragma unroll
    for (int j = 0; j < 3; j++) acc[j] = {0.f, 0.f, 0.f, 0.f};

    const float* xrow = x + (size_t)(m0 + arow) * EE + akq;
    f32x4 xreg = *(const f32x4*)xrow;

    for (int k0 = 0; k0 < EE; k0 += 64) {
        const int buf = (k0 >> 6) & 1;
        bf16x4 ab = {(bf16)xreg.x, (bf16)xreg.y, (bf16)xreg.z, (bf16)xreg.w};
        *(bf16x4*)&Abuf[buf][arow][akq] = ab;
        __syncthreads();
        if (k0 + 64 < EE) xreg = *(const f32x4*)(xrow + k0 + 64);

#pragma unroll
        for (int kk = 0; kk < 64; kk += 32) {
            bf16x8 af = *(const bf16x8*)&Abuf[buf][msub * 16 + col][kk + quad * 8];
#pragma unroll
            for (int j = 0; j < 3; j++) {
                const bf16* wp = &Wb[(size_t)((grp * 3 + j) * 16 + col) * EE + k0 + kk + quad * 8];
                acc[j] = __builtin_amdgcn_mfma_f32_16x16x32_bf16(af, *(const bf16x8*)wp,
                                                                 acc[j], 0, 0, 0);
            }
        }
        // single barrier per chunk: buf is rewritten 2 iters later, after the
        // next barrier proves all waves finished reading it.
    }

    const int mr0  = m0 + msub * 16 + quad * 4;  // C/D: row=quad*4+r, col=lane&15
    const int bidx = mr0 >> 11;
    const int sloc = mr0 & 2047;
    const int ck   = sloc >> 6;
    const int so   = sloc & 63;
#pragma unroll
    for (int j = 0; j < 3; j++) {
        int gn = grp * 3 + j;
        int t4 = gn & 3;
        int h  = t4 * 16 + col;
        if (gn < 4) {
            float bias = bq[h];
#pragma unroll
            for (int r = 0; r < 4; r++)
                Q[(size_t)(mr0 + r) * HH + h] = (bf16)((acc[j][r] + bias) * 0.125f);
        } else if (gn < 8) {
            float bias = bk[h];
#pragma unroll
            for (int r = 0; r < 4; r++)
                K[(size_t)(mr0 + r) * HH + h] = (bf16)(acc[j][r] + bias);
        } else {
            float bias = bv[h];
            bf16x4 pk = {(bf16)(acc[j][0] + bias), (bf16)(acc[j][1] + bias),
                         (bf16)(acc[j][2] + bias), (bf16)(acc[j][3] + bias)};
            *(bf16x4*)&Vt[(size_t)bidx * SS * HH + (size_t)ck * HH * 64 + h * 64 + so] = pk;
        }
    }
}

// ---------------------------------------------------------------------------
// Attention chunk loop for one q-tile, 8-wave round-robin, K prefetch.
// S^T = mfma(A=K, B=Q): lane holds S[q=q0+col][k=c*64+n4*16+quad*4+r].
// Fixed-max softmax (scores |s|<~6): p=exp(s), masked->0, no rescale.
// P C-layout regs == A-frag of 16x16x16 -> PV direct from registers.
// ---------------------------------------------------------------------------
__device__ __forceinline__ void attn_tile8(
    const bf16* __restrict__ Kb, const bf16* __restrict__ Vb,
    bf16x8 qb0, bf16x8 qb1, int q0, int nch,
    int wave, int col, int quad, f32x4 (&o)[4], float& lsum) {
    int c = wave;
    if (c >= nch) return;

    bf16x8 ka[8];
    {
        const bf16* Kc = Kb + (size_t)c * 64 * HH;
#pragma unroll
        for (int n4 = 0; n4 < 4; n4++) {
            ka[n4 * 2]     = *(const bf16x8*)&Kc[(n4 * 16 + col) * HH + quad * 8];
            ka[n4 * 2 + 1] = *(const bf16x8*)&Kc[(n4 * 16 + col) * HH + 32 + quad * 8];
        }
    }

    for (; c < nch; c += 8) {
        const bf16* Vc = Vb + (size_t)c * 64 * HH;
        // V loads early: land behind QK+exp latency
        bf16x4 vv[16];
#pragma unroll
        for (int h4 = 0; h4 < 4; h4++)
#pragma unroll
            for (int n4 = 0; n4 < 4; n4++)
                vv[h4 * 4 + n4] =
                    *(const bf16x4*)&Vc[(h4 * 16 + col) * 64 + n4 * 16 + quad * 4];

        f32x4 s[4];
#pragma unroll
        for (int n4 = 0; n4 < 4; n4++) {
            f32x4 z = {0.f, 0.f, 0.f, 0.f};
            z     = __builtin_amdgcn_mfma_f32_16x16x32_bf16(ka[n4 * 2], qb0, z, 0, 0, 0);
            s[n4] = __builtin_amdgcn_mfma_f32_16x16x32_bf16(ka[n4 * 2 + 1], qb1, z, 0, 0, 0);
        }

        // prefetch next chunk's K frags (independent of everything below)
        const int cn = c + 8;
        if (cn < nch) {
            const bf16* Kn = Kb + (size_t)cn * 64 * HH;
#pragma unroll
            for (int n4 = 0; n4 < 4; n4++) {
                ka[n4 * 2]     = *(const bf16x8*)&Kn[(n4 * 16 + col) * HH + quad * 8];
                ka[n4 * 2 + 1] = *(const bf16x8*)&Kn[(n4 * 16 + col) * HH + 32 + quad * 8];
            }
        }

        const bool diag = (c == nch - 1);
        short4v p4[4];
#pragma unroll
        for (int n4 = 0; n4 < 4; n4++) {
            bf16x4 pb;
#pragma unroll
            for (int r = 0; r < 4; r++) {
                float p = __expf(s[n4][r]);
                if (diag) {
                    int kr = c * 64 + n4 * 16 + quad * 4 + r;
                    if (kr > q0 + col) p = 0.f;
                }
                lsum += p;
                pb[r] = (bf16)p;
            }
            p4[n4] = __builtin_bit_cast(short4v, pb);
        }
#pragma unroll
        for (int h4 = 0; h4 < 4; h4++)
#pragma unroll
            for (int n4 = 0; n4 < 4; n4++)
                o[h4] = __builtin_amdgcn_mfma_f32_16x16x16bf16_1k(
                    p4[n4], __builtin_bit_cast(short4v, vv[h4 * 4 + n4]), o[h4], 0, 0, 0);
    }
}

// Block = 8 waves (512 thr), q-tile pair (bx, 127-bx) = 33 chunks/block
// uniform. Waves round-robin chunks per tile; additive LDS merge.
// Grid (64, 8) -> 2 blocks/CU, 16 waves/CU = 4 waves/SIMD.
__global__ __launch_bounds__(512, 4) void attn_mfma(
    const bf16* __restrict__ Q, const bf16* __restrict__ K,
    const bf16* __restrict__ Vt, float* __restrict__ out) {
    __shared__ __align__(16) float po[8][2][16][68];  // 69.6 KB
    __shared__ float pl[8][2][16];

    const int b    = blockIdx.y;
    const int bx   = blockIdx.x;
    const int wave = threadIdx.x >> 6;
    const int lane = threadIdx.x & 63;
    const int col  = lane & 15;
    const int quad = lane >> 4;

    const int qlo = bx, qhi = 127 - bx;
    const int nlo = qlo / 4 + 1, nhi = qhi / 4 + 1;

    const bf16* Qb = Q + (size_t)b * SS * HH;
    const bf16* Kb = K + (size_t)b * SS * HH;
    const bf16* Vb = Vt + (size_t)b * SS * HH;

    bf16x8 qlo0 = *(const bf16x8*)&Qb[(size_t)(qlo * 16 + col) * HH + quad * 8];
    bf16x8 qlo1 = *(const bf16x8*)&Qb[(size_t)(qlo * 16 + col) * HH + 32 + quad * 8];
    bf16x8 qhi0 = *(const bf16x8*)&Qb[(size_t)(qhi * 16 + col) * HH + quad * 8];
    bf16x8 qhi1 = *(const bf16x8*)&Qb[(size_t)(qhi * 16 + col) * HH + 32 + quad * 8];

    f32x4 olo[4], ohi[4];
#pragma unroll
    for (int n = 0; n < 4; n++) {
        olo[n] = {0.f, 0.f, 0.f, 0.f};
        ohi[n] = {0.f, 0.f, 0.f, 0.f};
    }
    float llo = 0.f, lhi = 0.f;

    attn_tile8(Kb, Vb, qlo0, qlo1, qlo * 16, nlo, wave, col, quad, olo, llo);
    attn_tile8(Kb, Vb, qhi0, qhi1, qhi * 16, nhi, wave, col, quad, ohi, lhi);

    // reduce l across the 4 quads (same q = col)
    llo += __shfl_xor(llo, 16); llo += __shfl_xor(llo, 32);
    lhi += __shfl_xor(lhi, 16); lhi += __shfl_xor(lhi, 32);
    if (quad == 0) { pl[wave][0][col] = llo; pl[wave][1][col] = lhi; }

#pragma unroll
    for (int h4 = 0; h4 < 4; h4++)
#pragma unroll
        for (int r = 0; r < 4; r++) {
            po[wave][0][quad * 4 + r][h4 * 16 + col] = olo[h4][r];
            po[wave][1][quad * 4 + r][h4 * 16 + col] = ohi[h4][r];
        }
    __syncthreads();

    // additive merge + normalize + store: 2048 outputs, 4 per thread
    const int tid = threadIdx.x;
    const int t   = tid >> 8;          // tile 0=lo, 1=hi
    const int q   = (tid >> 4) & 15;
    const int h0  = (tid & 15) * 4;
    float l = 0.f;
#pragma unroll
    for (int w = 0; w < 8; w++) l += pl[w][t][q];
    f32x4 s = {0.f, 0.f, 0.f, 0.f};
#pragma unroll
    for (int w = 0; w < 8; w++) s += *(const f32x4*)&po[w][t][q][h0];
    s *= (1.f / l);
    const int qt = t ? qhi : qlo;
    *(f32x4*)&out[((size_t)b * SS + qt * 16 + q) * HH + h0] = s;
}

extern "C" void kernel_launch(void* const* d_in, const int* in_sizes, int n_in,
                              void* d_out, int out_size, void* d_ws, size_t ws_size,
                              hipStream_t stream) {
    const float* x  = (const float*)d_in[0];
    const float* Wq = (const float*)d_in[1];
    const float* bq = (const float*)d_in[2];
    const float* Wk = (const float*)d_in[3];
    const float* bk = (const float*)d_in[4];
    const float* Wv = (const float*)d_in[5];
    const float* bv = (const float*)d_in[6];
    float* out = (float*)d_out;

    bf16* Q  = (bf16*)d_ws;                         // 2 MB
    bf16* K  = Q + (size_t)MM * HH;                 // 2 MB
    bf16* Vt = K + (size_t)MM * HH;                 // 2 MB (chunk-tiled)
    bf16* Wb = Vt + (size_t)MM * HH;                // 384 KB

    conv_w<<<96, 256, 0, stream>>>(Wq, Wk, Wv, Wb);
    qkv_mfma<<<MM / 32, 512, 0, stream>>>(x, Wb, bq, bk, bv, Q, K, Vt);
    dim3 g(64, BB);
    attn_mfma<<<g, 512, 0, stream>>>(Q, K, Vt, out);
}

// Round 7
// 175.544 us; speedup vs baseline: 1.1191x; 1.1191x over previous
//
#include <hip/hip_runtime.h>
#include <hip/hip_bf16.h>

// B=8, S=2048, E=1024, H=64. fp32 in/out, bf16 MFMA compute.
// conv_w: W->bf16. qkv_mfma: LDS-tiled GEMM (r4 version verbatim: m16 x n192
// x k1024, BK=64, reg prefetch, 1024 blocks). attn_mfma: transposed-S flash
// attention; paired q-tiles (bx, 127-bx) unified into one 33-chunk sequence
// split round-robin over 8 waves (uniform work), single-tile live state +
// K-frag prefetch, sized to stay under 128 VGPRs (r6 spilled at ~150).

#define BB 8
#define SS 2048
#define EE 1024
#define HH 64
#define MM (BB * SS)

typedef __bf16 bf16;
typedef __attribute__((ext_vector_type(8))) __bf16 bf16x8;
typedef __attribute__((ext_vector_type(4))) __bf16 bf16x4;
typedef __attribute__((ext_vector_type(4))) float f32x4;
typedef __attribute__((ext_vector_type(4))) short short4v;

// ---------------------------------------------------------------------------
// [Wq;Wk;Wv] (192x1024 fp32) -> Wb (bf16). 96 blocks.
// ---------------------------------------------------------------------------
__global__ __launch_bounds__(256) void conv_w(const float* __restrict__ Wq,
                                              const float* __restrict__ Wk,
                                              const float* __restrict__ Wv,
                                              bf16* __restrict__ Wb) {
    int i = (blockIdx.x * 256 + threadIdx.x) * 8;
    const float* src;
    int j;
    if (i < 65536)        { src = Wq; j = i; }
    else if (i < 131072)  { src = Wk; j = i - 65536; }
    else                  { src = Wv; j = i - 131072; }
    f32x4 a = *(const f32x4*)(src + j);
    f32x4 b = *(const f32x4*)(src + j + 4);
    bf16x8 o = {(bf16)a.x, (bf16)a.y, (bf16)a.z, (bf16)a.w,
                (bf16)b.x, (bf16)b.y, (bf16)b.z, (bf16)b.w};
    *(bf16x8*)(Wb + i) = o;
}

// ---------------------------------------------------------------------------
// QKV GEMM, LDS-tiled (r4 version). Block = 256 thr (4 waves), m-tile 16,
// n = 192 (12 tiles; wave w owns n-tiles w*3..w*3+2), BK=64, reg prefetch.
// Grid 1024 -> 4 blocks/CU.
// ---------------------------------------------------------------------------
__global__ __launch_bounds__(256) void qkv_mfma(
    const float* __restrict__ x, const bf16* __restrict__ Wb,
    const float* __restrict__ bq, const float* __restrict__ bk,
    const float* __restrict__ bv,
    bf16* __restrict__ Q, bf16* __restrict__ K, bf16* __restrict__ Vt) {
    __shared__ __align__(16) bf16 Abuf[16][72];
    __shared__ __align__(16) bf16 Wbuf[192][72];

    const int tid  = threadIdx.x;
    const int wave = tid >> 6;
    const int lane = tid & 63;
    const int col  = lane & 15;
    const int quad = lane >> 4;
    const int m0   = blockIdx.x * 16;

    const int arow = tid >> 4;
    const int akq  = (tid & 15) * 4;
    const int wrow = tid >> 3;
    const int wkq  = (tid & 7) * 8;

    f32x4 acc[3];
#pragma unroll
    for (int j = 0; j < 3; j++) acc[j] = {0.f, 0.f, 0.f, 0.f};

    f32x4 areg = *(const f32x4*)&x[(size_t)(m0 + arow) * EE + akq];
    bf16x8 wreg[6];
#pragma unroll
    for (int i = 0; i < 6; i++)
        wreg[i] = *(const bf16x8*)&Wb[(size_t)(wrow + 32 * i) * EE + wkq];

    for (int k0 = 0; k0 < EE; k0 += 64) {
        bf16x4 ab = {(bf16)areg.x, (bf16)areg.y, (bf16)areg.z, (bf16)areg.w};
        *(bf16x4*)&Abuf[arow][akq] = ab;
#pragma unroll
        for (int i = 0; i < 6; i++)
            *(bf16x8*)&Wbuf[wrow + 32 * i][wkq] = wreg[i];
        __syncthreads();

        if (k0 + 64 < EE) {
            areg = *(const f32x4*)&x[(size_t)(m0 + arow) * EE + k0 + 64 + akq];
#pragma unroll
            for (int i = 0; i < 6; i++)
                wreg[i] = *(const bf16x8*)&Wb[(size_t)(wrow + 32 * i) * EE + k0 + 64 + wkq];
        }

#pragma unroll
        for (int kk = 0; kk < 64; kk += 32) {
            bf16x8 af = *(const bf16x8*)&Abuf[col][kk + quad * 8];
#pragma unroll
            for (int j = 0; j < 3; j++) {
                bf16x8 bf_ = *(const bf16x8*)&Wbuf[(wave * 3 + j) * 16 + col][kk + quad * 8];
                acc[j] = __builtin_amdgcn_mfma_f32_16x16x32_bf16(af, bf_, acc[j], 0, 0, 0);
            }
        }
        __syncthreads();
    }

    const int mr0  = m0 + quad * 4;
    const int bidx = mr0 >> 11;
    const int sloc = mr0 & 2047;
    const int ck   = sloc >> 6;
    const int so   = sloc & 63;
#pragma unroll
    for (int j = 0; j < 3; j++) {
        int gn = wave * 3 + j;
        int t4 = gn & 3;
        int h  = t4 * 16 + col;
        if (gn < 4) {
            float bias = bq[h];
#pragma unroll
            for (int r = 0; r < 4; r++)
                Q[(size_t)(mr0 + r) * HH + h] = (bf16)((acc[j][r] + bias) * 0.125f);
        } else if (gn < 8) {
            float bias = bk[h];
#pragma unroll
            for (int r = 0; r < 4; r++)
                K[(size_t)(mr0 + r) * HH + h] = (bf16)(acc[j][r] + bias);
        } else {
            float bias = bv[h];
            bf16x4 pk = {(bf16)(acc[j][0] + bias), (bf16)(acc[j][1] + bias),
                         (bf16)(acc[j][2] + bias), (bf16)(acc[j][3] + bias)};
            *(bf16x4*)&Vt[(size_t)bidx * SS * HH + (size_t)ck * HH * 64 + h * 64 + so] = pk;
        }
    }
}

// ---------------------------------------------------------------------------
// Flash attention, transposed-S (A=K, B=Q): lane holds S[q=col][k=quad*4+r].
// Fixed-max softmax (|s|<~6): p=exp(s), masked->0, additive merge.
// P C-layout regs == A-frag of 16x16x16 -> PV direct from regs; V from
// chunk-tiled Vt (128B rows). Block = 8 waves; q-tile pair (bx, 127-bx)
// unified into j in [0,33) (nlo+nhi==33): wave w takes j = w, w+8, ...
// (uniform ~4.1 chunks/wave, tile crossing is monotone -> q-frags reloaded
// once). Live state ~110 VGPRs (no vv array -> no spill).
// Grid (64,8), 69.6 KB LDS -> 2 blocks/CU, 4 waves/SIMD.
// ---------------------------------------------------------------------------
__global__ __launch_bounds__(512, 4) void attn_mfma(
    const bf16* __restrict__ Q, const bf16* __restrict__ K,
    const bf16* __restrict__ Vt, float* __restrict__ out) {
    __shared__ __align__(16) float po[8][2][16][68];  // 69.6 KB
    __shared__ float pl[8][2][16];

    const int b    = blockIdx.y;
    const int bx   = blockIdx.x;
    const int wave = threadIdx.x >> 6;
    const int lane = threadIdx.x & 63;
    const int col  = lane & 15;
    const int quad = lane >> 4;

    const int qlo = bx, qhi = 127 - bx;
    const int nlo = qlo / 4 + 1;
    const int nhi = qhi / 4 + 1;   // nlo + nhi == 33 for all bx

    const bf16* Qb = Q + (size_t)b * SS * HH;
    const bf16* Kb = K + (size_t)b * SS * HH;
    const bf16* Vb = Vt + (size_t)b * SS * HH;

    f32x4 olo[4], ohi[4];
#pragma unroll
    for (int n = 0; n < 4; n++) {
        olo[n] = {0.f, 0.f, 0.f, 0.f};
        ohi[n] = {0.f, 0.f, 0.f, 0.f};
    }
    float llo = 0.f, lhi = 0.f;

    bf16x8 qb0, qb1;
    int curTile = -1;

    // prefetch K frags for first j
    int j = wave;
    bf16x8 ka[8];
    {
        int isHi = (j >= nlo);
        int c    = isHi ? j - nlo : j;
        const bf16* Kc = Kb + (size_t)c * 64 * HH;
#pragma unroll
        for (int n4 = 0; n4 < 4; n4++) {
            ka[n4 * 2]     = *(const bf16x8*)&Kc[(n4 * 16 + col) * HH + quad * 8];
            ka[n4 * 2 + 1] = *(const bf16x8*)&Kc[(n4 * 16 + col) * HH + 32 + quad * 8];
        }
    }

    for (; j < 33; j += 8) {
        const int isHi = (j >= nlo);
        const int c    = isHi ? j - nlo : j;
        const int nch  = isHi ? nhi : nlo;
        const int qt   = isHi ? qhi : qlo;

        if (isHi != curTile) {  // at most twice per wave (init + crossing)
            curTile = isHi;
            qb0 = *(const bf16x8*)&Qb[(size_t)(qt * 16 + col) * HH + quad * 8];
            qb1 = *(const bf16x8*)&Qb[(size_t)(qt * 16 + col) * HH + 32 + quad * 8];
        }

        f32x4 s[4];
#pragma unroll
        for (int n4 = 0; n4 < 4; n4++) {
            f32x4 z = {0.f, 0.f, 0.f, 0.f};
            z      = __builtin_amdgcn_mfma_f32_16x16x32_bf16(ka[n4 * 2], qb0, z, 0, 0, 0);
            s[n4]  = __builtin_amdgcn_mfma_f32_16x16x32_bf16(ka[n4 * 2 + 1], qb1, z, 0, 0, 0);
        }

        // prefetch next j's K frags (independent of the rest of the chunk)
        const int jn = j + 8;
        if (jn < 33) {
            int isHi2 = (jn >= nlo);
            int c2    = isHi2 ? jn - nlo : jn;
            const bf16* Kn = Kb + (size_t)c2 * 64 * HH;
#pragma unroll
            for (int n4 = 0; n4 < 4; n4++) {
                ka[n4 * 2]     = *(const bf16x8*)&Kn[(n4 * 16 + col) * HH + quad * 8];
                ka[n4 * 2 + 1] = *(const bf16x8*)&Kn[(n4 * 16 + col) * HH + 32 + quad * 8];
            }
        }

        const bool diag = (c == nch - 1);
        float rs = 0.f;
        short4v p4[4];
#pragma unroll
        for (int n4 = 0; n4 < 4; n4++) {
            bf16x4 pb;
#pragma unroll
            for (int r = 0; r < 4; r++) {
                float p = __expf(s[n4][r]);
                if (diag) {
                    int kr = c * 64 + n4 * 16 + quad * 4 + r;
                    if (kr > qt * 16 + col) p = 0.f;
                }
                rs += p;
                pb[r] = (bf16)p;
            }
            p4[n4] = __builtin_bit_cast(short4v, pb);
        }

        const bf16* Vc = Vb + (size_t)c * 64 * HH;
        if (!isHi) {
            llo += rs;
#pragma unroll
            for (int h4 = 0; h4 < 4; h4++)
#pragma unroll
                for (int n4 = 0; n4 < 4; n4++) {
                    bf16x4 vv = *(const bf16x4*)&Vc[(h4 * 16 + col) * 64 + n4 * 16 + quad * 4];
                    olo[h4] = __builtin_amdgcn_mfma_f32_16x16x16bf16_1k(
                        p4[n4], __builtin_bit_cast(short4v, vv), olo[h4], 0, 0, 0);
                }
        } else {
            lhi += rs;
#pragma unroll
            for (int h4 = 0; h4 < 4; h4++)
#pragma unroll
                for (int n4 = 0; n4 < 4; n4++) {
                    bf16x4 vv = *(const bf16x4*)&Vc[(h4 * 16 + col) * 64 + n4 * 16 + quad * 4];
                    ohi[h4] = __builtin_amdgcn_mfma_f32_16x16x16bf16_1k(
                        p4[n4], __builtin_bit_cast(short4v, vv), ohi[h4], 0, 0, 0);
                }
        }
    }

    // l: reduce across the 4 quads (same q = col)
    llo += __shfl_xor(llo, 16); llo += __shfl_xor(llo, 32);
    lhi += __shfl_xor(lhi, 16); lhi += __shfl_xor(lhi, 32);
    if (quad == 0) { pl[wave][0][col] = llo; pl[wave][1][col] = lhi; }

#pragma unroll
    for (int h4 = 0; h4 < 4; h4++)
#pragma unroll
        for (int r = 0; r < 4; r++) {
            po[wave][0][quad * 4 + r][h4 * 16 + col] = olo[h4][r];
            po[wave][1][quad * 4 + r][h4 * 16 + col] = ohi[h4][r];
        }
    __syncthreads();

    // additive merge + normalize + store: 2048 outputs, 4 per thread
    const int tid = threadIdx.x;
    const int t   = tid >> 8;          // 0 = lo tile, 1 = hi tile
    const int q   = (tid >> 4) & 15;
    const int h0  = (tid & 15) * 4;
    float l = 0.f;
#pragma unroll
    for (int w = 0; w < 8; w++) l += pl[w][t][q];
    f32x4 s = {0.f, 0.f, 0.f, 0.f};
#pragma unroll
    for (int w = 0; w < 8; w++) s += *(const f32x4*)&po[w][t][q][h0];
    s *= (1.f / l);
    const int qt = t ? qhi : qlo;
    *(f32x4*)&out[((size_t)b * SS + qt * 16 + q) * HH + h0] = s;
}

extern "C" void kernel_launch(void* const* d_in, const int* in_sizes, int n_in,
                              void* d_out, int out_size, void* d_ws, size_t ws_size,
                              hipStream_t stream) {
    const float* x  = (const float*)d_in[0];
    const float* Wq = (const float*)d_in[1];
    const float* bq = (const float*)d_in[2];
    const float* Wk = (const float*)d_in[3];
    const float* bk = (const float*)d_in[4];
    const float* Wv = (const float*)d_in[5];
    const float* bv = (const float*)d_in[6];
    float* out = (float*)d_out;

    bf16* Q  = (bf16*)d_ws;                         // 2 MB
    bf16* K  = Q + (size_t)MM * HH;                 // 2 MB
    bf16* Vt = K + (size_t)MM * HH;                 // 2 MB (chunk-tiled)
    bf16* Wb = Vt + (size_t)MM * HH;                // 384 KB

    conv_w<<<96, 256, 0, stream>>>(Wq, Wk, Wv, Wb);
    qkv_mfma<<<MM / 16, 256, 0, stream>>>(x, Wb, bq, bk, bv, Q, K, Vt);
    dim3 g(64, BB);
    attn_mfma<<<g, 512, 0, stream>>>(Q, K, Vt, out);
}

// Round 8
// 151.527 us; speedup vs baseline: 1.2965x; 1.1585x over previous
//
#include <hip/hip_runtime.h>
#include <hip/hip_bf16.h>

// B=8, S=2048, E=1024, H=64. fp32 in/out, bf16 MFMA compute.
// conv_w: W->bf16. qkv_mfma: r4 LDS GEMM + per-block k0 phase stagger
// (anti channel-camping); K and Vt stored XOR-SWIZZLED (16B unit ^= row&7)
// for conflict-free LDS frag reads downstream. attn_mfma: chunk K/V staged
// to LDS once per block, shared by 4 waves (12x fewer L2 requests than
// per-wave gathers); supertile pair (p,31-p), parity-split chunks, fixed-max
// additive softmax, partials to out/ws. attn_fin: merge + normalize.

#define BB 8
#define SS 2048
#define EE 1024
#define HH 64
#define MM (BB * SS)

typedef __bf16 bf16;
typedef __attribute__((ext_vector_type(8))) __bf16 bf16x8;
typedef __attribute__((ext_vector_type(4))) __bf16 bf16x4;
typedef __attribute__((ext_vector_type(4))) float f32x4;
typedef __attribute__((ext_vector_type(4))) short short4v;

// ---------------------------------------------------------------------------
// [Wq;Wk;Wv] (192x1024 fp32) -> Wb (bf16). 96 blocks.
// ---------------------------------------------------------------------------
__global__ __launch_bounds__(256) void conv_w(const float* __restrict__ Wq,
                                              const float* __restrict__ Wk,
                                              const float* __restrict__ Wv,
                                              bf16* __restrict__ Wb) {
    int i = (blockIdx.x * 256 + threadIdx.x) * 8;
    const float* src;
    int j;
    if (i < 65536)        { src = Wq; j = i; }
    else if (i < 131072)  { src = Wk; j = i - 65536; }
    else                  { src = Wv; j = i - 131072; }
    f32x4 a = *(const f32x4*)(src + j);
    f32x4 b = *(const f32x4*)(src + j + 4);
    bf16x8 o = {(bf16)a.x, (bf16)a.y, (bf16)a.z, (bf16)a.w,
                (bf16)b.x, (bf16)b.y, (bf16)b.z, (bf16)b.w};
    *(bf16x8*)(Wb + i) = o;
}

// ---------------------------------------------------------------------------
// QKV GEMM (r4 structure). Block = 256 thr (4 waves), m-tile 16, n=192,
// BK=64, reg prefetch. k0 starts at a per-block phase so the chip's blocks
// spread over all 16 k-phases (x rows are 4KB-strided: same-phase staging
// camps on 1-2 L2 channels chip-wide). K/Vt written with unit^=(row&7)
// swizzle for the attention kernel's LDS layout.
// ---------------------------------------------------------------------------
__global__ __launch_bounds__(256) void qkv_mfma(
    const float* __restrict__ x, const bf16* __restrict__ Wb,
    const float* __restrict__ bq, const float* __restrict__ bk,
    const float* __restrict__ bv,
    bf16* __restrict__ Q, bf16* __restrict__ K, bf16* __restrict__ Vt) {
    __shared__ __align__(16) bf16 Abuf[16][72];
    __shared__ __align__(16) bf16 Wbuf[192][72];

    const int tid  = threadIdx.x;
    const int wave = tid >> 6;
    const int lane = tid & 63;
    const int col  = lane & 15;
    const int quad = lane >> 4;
    const int m0   = blockIdx.x * 16;
    const int kph  = (blockIdx.x & 15) << 6;  // k0 phase 0,64,...,960

    const int arow = tid >> 4;
    const int akq  = (tid & 15) * 4;
    const int wrow = tid >> 3;
    const int wkq  = (tid & 7) * 8;

    f32x4 acc[3];
#pragma unroll
    for (int j = 0; j < 3; j++) acc[j] = {0.f, 0.f, 0.f, 0.f};

    f32x4 areg = *(const f32x4*)&x[(size_t)(m0 + arow) * EE + kph + akq];
    bf16x8 wreg[6];
#pragma unroll
    for (int i = 0; i < 6; i++)
        wreg[i] = *(const bf16x8*)&Wb[(size_t)(wrow + 32 * i) * EE + kph + wkq];

    for (int it = 0; it < 16; it++) {
        bf16x4 ab = {(bf16)areg.x, (bf16)areg.y, (bf16)areg.z, (bf16)areg.w};
        *(bf16x4*)&Abuf[arow][akq] = ab;
#pragma unroll
        for (int i = 0; i < 6; i++)
            *(bf16x8*)&Wbuf[wrow + 32 * i][wkq] = wreg[i];
        __syncthreads();

        if (it < 15) {
            int k0n = (kph + (it + 1) * 64) & 1023;
            areg = *(const f32x4*)&x[(size_t)(m0 + arow) * EE + k0n + akq];
#pragma unroll
            for (int i = 0; i < 6; i++)
                wreg[i] = *(const bf16x8*)&Wb[(size_t)(wrow + 32 * i) * EE + k0n + wkq];
        }

#pragma unroll
        for (int kk = 0; kk < 64; kk += 32) {
            bf16x8 af = *(const bf16x8*)&Abuf[col][kk + quad * 8];
#pragma unroll
            for (int j = 0; j < 3; j++) {
                bf16x8 bf_ = *(const bf16x8*)&Wbuf[(wave * 3 + j) * 16 + col][kk + quad * 8];
                acc[j] = __builtin_amdgcn_mfma_f32_16x16x32_bf16(af, bf_, acc[j], 0, 0, 0);
            }
        }
        __syncthreads();
    }

    const int mr0  = m0 + quad * 4;
    const int bidx = mr0 >> 11;
    const int sloc = mr0 & 2047;
    const int ck   = sloc >> 6;
    const int so   = sloc & 63;
#pragma unroll
    for (int j = 0; j < 3; j++) {
        int gn = wave * 3 + j;
        int t4 = gn & 3;
        int h  = t4 * 16 + col;
        if (gn < 4) {
            float bias = bq[h];
#pragma unroll
            for (int r = 0; r < 4; r++)
                Q[(size_t)(mr0 + r) * HH + h] = (bf16)((acc[j][r] + bias) * 0.125f);
        } else if (gn < 8) {
            float bias = bk[h];
#pragma unroll
            for (int r = 0; r < 4; r++) {
                int s = mr0 + r;                     // swizzled K store
                int u = (h >> 3) ^ (s & 7);
                K[(size_t)s * HH + u * 8 + (h & 7)] = (bf16)(acc[j][r] + bias);
            }
        } else {
            float bias = bv[h];
            bf16x4 pk = {(bf16)(acc[j][0] + bias), (bf16)(acc[j][1] + bias),
                         (bf16)(acc[j][2] + bias), (bf16)(acc[j][3] + bias)};
            int u = (so >> 3) ^ (h & 7);             // swizzled Vt store
            *(bf16x4*)&Vt[(size_t)bidx * SS * HH + (size_t)ck * 4096 +
                          h * 64 + u * 8 + (so & 7)] = pk;
        }
    }
}

// ---------------------------------------------------------------------------
// Flash attention, LDS-shared chunks. Block = 256 thr (4 waves); supertile
// pair lo=p (64 rows), hi=31-p; wave w owns 16-row subtile of each. Unified
// chunk list j=0..32 (j<nlo -> lo chunk j, else hi chunk j-nlo); block par
// takes j===par (mod 2). Per chunk: 16KB K/V staged to LDS (coalesced,
// double-buffered, ONE barrier), all 4 waves compute their subtile from LDS
// (XOR-swizzled reads, 2-way conflicts = free). Transposed-S + fixed-max
// softmax + register PV as r5-r7. Partials (o,l): par0 -> out/l0,
// par1 -> o1/l1 (additive merge in attn_fin).
// ---------------------------------------------------------------------------
__global__ __launch_bounds__(256) void attn_mfma(
    const bf16* __restrict__ Q, const bf16* __restrict__ K,
    const bf16* __restrict__ Vt, float* __restrict__ o0,
    float* __restrict__ o1, float* __restrict__ l0, float* __restrict__ l1) {
    __shared__ __align__(16) bf16 kv[2][8192];  // 32 KB: [buf][K 4096 | V 4096]

    const int p    = blockIdx.x;      // 0..15
    const int b    = blockIdx.y;
    const int par  = blockIdx.z;      // 0..1
    const int tid  = threadIdx.x;
    const int wave = tid >> 6;
    const int lane = tid & 63;
    const int col  = lane & 15;
    const int quad = lane >> 4;

    const int nlo = p + 1, nhi = 32 - p;          // nlo + nhi == 33
    const int lo0 = p * 64 + wave * 16;
    const int hi0 = (31 - p) * 64 + wave * 16;

    const bf16* Qb = Q + (size_t)b * SS * HH;
    const bf16* Kb = K + (size_t)b * SS * HH;
    const bf16* Vb = Vt + (size_t)b * SS * HH;

    bf16x8 qlo0 = *(const bf16x8*)&Qb[(size_t)(lo0 + col) * HH + quad * 8];
    bf16x8 qlo1 = *(const bf16x8*)&Qb[(size_t)(lo0 + col) * HH + 32 + quad * 8];
    bf16x8 qhi0 = *(const bf16x8*)&Qb[(size_t)(hi0 + col) * HH + quad * 8];
    bf16x8 qhi1 = *(const bf16x8*)&Qb[(size_t)(hi0 + col) * HH + 32 + quad * 8];

    f32x4 olo[4], ohi[4];
#pragma unroll
    for (int n = 0; n < 4; n++) {
        olo[n] = {0.f, 0.f, 0.f, 0.f};
        ohi[n] = {0.f, 0.f, 0.f, 0.f};
    }
    float llo = 0.f, lhi = 0.f;

    // prefetch first chunk into registers (16KB/block = 64B/thread)
    bf16x8 greg[4];
    {
        int c0 = (par >= nlo) ? par - nlo : par;
#pragma unroll
        for (int i = 0; i < 4; i++) {
            const bf16* g = (i < 2) ? Kb + (size_t)c0 * 4096 + i * 2048
                                    : Vb + (size_t)c0 * 4096 + (i - 2) * 2048;
            greg[i] = *(const bf16x8*)(g + tid * 8);
        }
    }

    int idx = 0;
    for (int j = par; j < 33; j += 2, idx++) {
        const int isHi = (j >= nlo);
        const int c    = isHi ? j - nlo : j;
        const int cur  = idx & 1;

        // commit staged regs to LDS buffer `cur` (safe: last read of `cur`
        // finished before the previous iteration's barrier)
#pragma unroll
        for (int i = 0; i < 4; i++)
            *(bf16x8*)&kv[cur][i * 2048 + tid * 8] = greg[i];

        // prefetch next chunk (flies during this chunk's compute)
        const int jn = j + 2;
        if (jn < 33) {
            int c2 = (jn >= nlo) ? jn - nlo : jn;
#pragma unroll
            for (int i = 0; i < 4; i++) {
                const bf16* g = (i < 2) ? Kb + (size_t)c2 * 4096 + i * 2048
                                        : Vb + (size_t)c2 * 4096 + (i - 2) * 2048;
                greg[i] = *(const bf16x8*)(g + tid * 8);
            }
        }
        __syncthreads();  // kv[cur] visible to all waves

        const bf16* lk = &kv[cur][0];
        const bf16* lv = &kv[cur][4096];
        const bf16x8 qb0 = isHi ? qhi0 : qlo0;
        const bf16x8 qb1 = isHi ? qhi1 : qlo1;

        f32x4 s[4];
#pragma unroll
        for (int n4 = 0; n4 < 4; n4++) {
            int sr = n4 * 16 + col;
            bf16x8 ka0 = *(const bf16x8*)&lk[sr * 64 + ((quad ^ (sr & 7)) * 8)];
            bf16x8 ka1 = *(const bf16x8*)&lk[sr * 64 + (((4 + quad) ^ (sr & 7)) * 8)];
            f32x4 z = {0.f, 0.f, 0.f, 0.f};
            z     = __builtin_amdgcn_mfma_f32_16x16x32_bf16(ka0, qb0, z, 0, 0, 0);
            s[n4] = __builtin_amdgcn_mfma_f32_16x16x32_bf16(ka1, qb1, z, 0, 0, 0);
        }

        const int  nch  = isHi ? nhi : nlo;
        const int  qrow = (isHi ? hi0 : lo0) + col;
        const bool diag = (c == nch - 1);
        float rs = 0.f;
        short4v p4[4];
#pragma unroll
        for (int n4 = 0; n4 < 4; n4++) {
            bf16x4 pb;
#pragma unroll
            for (int r = 0; r < 4; r++) {
                float pe = __expf(s[n4][r]);
                if (diag) {
                    int kr = c * 64 + n4 * 16 + quad * 4 + r;
                    if (kr > qrow) pe = 0.f;
                }
                rs += pe;
                pb[r] = (bf16)pe;
            }
            p4[n4] = __builtin_bit_cast(short4v, pb);
        }

        if (!isHi) {
            llo += rs;
#pragma unroll
            for (int h4 = 0; h4 < 4; h4++)
#pragma unroll
                for (int n4 = 0; n4 < 4; n4++) {
                    int vr = h4 * 16 + col;
                    int u  = n4 * 2 + (quad >> 1);
                    bf16x4 vv = *(const bf16x4*)&lv[vr * 64 + ((u ^ (vr & 7)) * 8) +
                                                    (quad & 1) * 4];
                    olo[h4] = __builtin_amdgcn_mfma_f32_16x16x16bf16_1k(
                        p4[n4], __builtin_bit_cast(short4v, vv), olo[h4], 0, 0, 0);
                }
        } else {
            lhi += rs;
#pragma unroll
            for (int h4 = 0; h4 < 4; h4++)
#pragma unroll
                for (int n4 = 0; n4 < 4; n4++) {
                    int vr = h4 * 16 + col;
                    int u  = n4 * 2 + (quad >> 1);
                    bf16x4 vv = *(const bf16x4*)&lv[vr * 64 + ((u ^ (vr & 7)) * 8) +
                                                    (quad & 1) * 4];
                    ohi[h4] = __builtin_amdgcn_mfma_f32_16x16x16bf16_1k(
                        p4[n4], __builtin_bit_cast(short4v, vv), ohi[h4], 0, 0, 0);
                }
        }
    }

    // l: reduce across the 4 quads (same q = col); direct global partials
    llo += __shfl_xor(llo, 16); llo += __shfl_xor(llo, 32);
    lhi += __shfl_xor(lhi, 16); lhi += __shfl_xor(lhi, 32);
    float* od = par ? o1 : o0;
    float* ld = par ? l1 : l0;
    if (quad == 0) {
        ld[b * SS + lo0 + col] = llo;
        ld[b * SS + hi0 + col] = lhi;
    }
#pragma unroll
    for (int h4 = 0; h4 < 4; h4++)
#pragma unroll
        for (int r = 0; r < 4; r++) {
            od[((size_t)b * SS + lo0 + quad * 4 + r) * HH + h4 * 16 + col] = olo[h4][r];
            od[((size_t)b * SS + hi0 + quad * 4 + r) * HH + h4 * 16 + col] = ohi[h4][r];
        }
}

// ---------------------------------------------------------------------------
// Merge the two parity partials: out = (out + o1) / (l0 + l1). 1024 blocks.
// ---------------------------------------------------------------------------
__global__ __launch_bounds__(256) void attn_fin(float* __restrict__ out,
                                                const float* __restrict__ o1,
                                                const float* __restrict__ l0,
                                                const float* __restrict__ l1) {
    int i   = blockIdx.x * 256 + threadIdx.x;  // f32x4 index, 262144 total
    int row = i >> 4;
    float inv = 1.f / (l0[row] + l1[row]);
    f32x4 a  = *(f32x4*)&out[i * 4];
    f32x4 bb = *(const f32x4*)&o1[i * 4];
    a = (a + bb) * inv;
    *(f32x4*)&out[i * 4] = a;
}

extern "C" void kernel_launch(void* const* d_in, const int* in_sizes, int n_in,
                              void* d_out, int out_size, void* d_ws, size_t ws_size,
                              hipStream_t stream) {
    const float* x  = (const float*)d_in[0];
    const float* Wq = (const float*)d_in[1];
    const float* bq = (const float*)d_in[2];
    const float* Wk = (const float*)d_in[3];
    const float* bk = (const float*)d_in[4];
    const float* Wv = (const float*)d_in[5];
    const float* bv = (const float*)d_in[6];
    float* out = (float*)d_out;

    bf16*  Q  = (bf16*)d_ws;                   // 2 MB
    bf16*  K  = Q + (size_t)MM * HH;           // 2 MB (swizzled)
    bf16*  Vt = K + (size_t)MM * HH;           // 2 MB (chunk-tiled, swizzled)
    bf16*  Wb = Vt + (size_t)MM * HH;          // 384 KB
    float* o1 = (float*)(Wb + (size_t)192 * EE);  // 4 MB (par1 partial o)
    float* l0 = o1 + (size_t)MM * HH;          // 64 KB
    float* l1 = l0 + MM;                       // 64 KB  (total ~11.0 MB)

    conv_w<<<96, 256, 0, stream>>>(Wq, Wk, Wv, Wb);
    qkv_mfma<<<MM / 16, 256, 0, stream>>>(x, Wb, bq, bk, bv, Q, K, Vt);
    dim3 g(16, BB, 2);
    attn_mfma<<<g, 256, 0, stream>>>(Q, K, Vt, out, o1, l0, l1);
    attn_fin<<<1024, 256, 0, stream>>>(out, o1, l0, l1);
}